// Round 1
// baseline (103.481 us; speedup 1.0000x reference)
//
#include <hip/hip_runtime.h>

// Batched 8192-point Walsh-Hadamard transform, one block per row.
// 256 threads x 32 floats (8 x float4) per thread.
// 13 butterfly stages split: ph1 elem bits {0,1,10,11,12} (contiguous load),
// ph2 {2,3,4}, ph3 {5,6,7}, ph4 {8,9} (contiguous store).
// LDS holds the row as 2048 float4 "quads"; quad q stored at swz(q) to kill
// bank conflicts on the strided phase-2/3/4 reads (XOR high bits into low 3).

static __device__ __forceinline__ void bfly(float4& a, float4& b) {
    float ax = a.x, ay = a.y, az = a.z, aw = a.w;
    a.x = ax + b.x; a.y = ay + b.y; a.z = az + b.z; a.w = aw + b.w;
    b.x = ax - b.x; b.y = ay - b.y; b.z = az - b.z; b.w = aw - b.w;
}

static __device__ __forceinline__ int swz(int q) { return q ^ ((q >> 3) & 7); }

__global__ __launch_bounds__(256) void wht8192_kernel(const float* __restrict__ in,
                                                      float* __restrict__ out) {
    __shared__ float4 lds[2048];  // 32 KB = one row
    const int t = threadIdx.x;    // 0..255
    const int l = t & 63;         // lane
    const int w = t >> 6;         // wave in block
    const size_t row = blockIdx.x;
    const float* __restrict__ rin  = in  + row * 8192;
    float* __restrict__       rout = out + row * 8192;

    float4 v[8];

    // ---- phase 1: ownership quads q = (k<<8)|t  (elements (k<<10)|(t<<2)) ----
    #pragma unroll
    for (int k = 0; k < 8; ++k)
        v[k] = *reinterpret_cast<const float4*>(rin + ((k << 10) | (t << 2)));

    // elem bits 0,1 (inside each quad)
    #pragma unroll
    for (int k = 0; k < 8; ++k) {
        float4 a = v[k];
        float s0 = a.x + a.y, d0 = a.x - a.y;
        float s1 = a.z + a.w, d1 = a.z - a.w;
        v[k].x = s0 + s1; v[k].z = s0 - s1;
        v[k].y = d0 + d1; v[k].w = d0 - d1;
    }
    // elem bits 10,11,12 (across k)
    bfly(v[0], v[1]); bfly(v[2], v[3]); bfly(v[4], v[5]); bfly(v[6], v[7]);
    bfly(v[0], v[2]); bfly(v[1], v[3]); bfly(v[4], v[6]); bfly(v[5], v[7]);
    bfly(v[0], v[4]); bfly(v[1], v[5]); bfly(v[2], v[6]); bfly(v[3], v[7]);

    #pragma unroll
    for (int k = 0; k < 8; ++k)
        lds[swz((k << 8) | t)] = v[k];
    __syncthreads();

    // ---- phase 2: ownership quads q = (t<<3)|j ; elem bits 2,3,4 ----
    #pragma unroll
    for (int j = 0; j < 8; ++j)
        v[j] = lds[swz((t << 3) | j)];

    bfly(v[0], v[1]); bfly(v[2], v[3]); bfly(v[4], v[5]); bfly(v[6], v[7]);
    bfly(v[0], v[2]); bfly(v[1], v[3]); bfly(v[4], v[6]); bfly(v[5], v[7]);
    bfly(v[0], v[4]); bfly(v[1], v[5]); bfly(v[2], v[6]); bfly(v[3], v[7]);

    #pragma unroll
    for (int j = 0; j < 8; ++j)
        lds[swz((t << 3) | j)] = v[j];
    __syncthreads();

    // ---- phase 3: q = (w<<9)|((l>>5)<<8)|(((l>>3)&3)<<6)|(m<<3)|(l&7) ;
    //      free q bits {3,4,5} = elem bits 5,6,7 ----
    const int base3 = (w << 9) | ((l >> 5) << 8) | (((l >> 3) & 3) << 6) | (l & 7);
    #pragma unroll
    for (int m = 0; m < 8; ++m)
        v[m] = lds[swz(base3 | (m << 3))];

    bfly(v[0], v[1]); bfly(v[2], v[3]); bfly(v[4], v[5]); bfly(v[6], v[7]);
    bfly(v[0], v[2]); bfly(v[1], v[3]); bfly(v[4], v[6]); bfly(v[5], v[7]);
    bfly(v[0], v[4]); bfly(v[1], v[5]); bfly(v[2], v[6]); bfly(v[3], v[7]);

    #pragma unroll
    for (int m = 0; m < 8; ++m)
        lds[swz(base3 | (m << 3))] = v[m];
    __syncthreads();

    // ---- phase 4: q = (w<<9)|(m<<6)|l ; free q bits {6,7,8}; butterfly
    //      q bits 6,7 = elem bits 8,9 (q bit 8 = elem bit 10, already done) ----
    #pragma unroll
    for (int m = 0; m < 8; ++m)
        v[m] = lds[swz((w << 9) | (m << 6) | l)];

    bfly(v[0], v[1]); bfly(v[2], v[3]); bfly(v[4], v[5]); bfly(v[6], v[7]);
    bfly(v[0], v[2]); bfly(v[1], v[3]); bfly(v[4], v[6]); bfly(v[5], v[7]);

    const float s = 0.011048543456039806f;  // 1/sqrt(8192)
    #pragma unroll
    for (int m = 0; m < 8; ++m) {
        float4 a = v[m];
        a.x *= s; a.y *= s; a.z *= s; a.w *= s;
        *reinterpret_cast<float4*>(rout + (((w << 9) | (m << 6) | l) << 2)) = a;
    }
}

extern "C" void kernel_launch(void* const* d_in, const int* in_sizes, int n_in,
                              void* d_out, int out_size, void* d_ws, size_t ws_size,
                              hipStream_t stream) {
    const float* x = (const float*)d_in[0];
    float* out = (float*)d_out;
    const int rows = out_size / 8192;  // 8192
    hipLaunchKernelGGL(wht8192_kernel, dim3(rows), dim3(256), 0, stream, x, out);
}

// Round 3
// 94.242 us; speedup vs baseline: 1.0980x; 1.0980x over previous
//
#include <hip/hip_runtime.h>

// Batched 8192-point Walsh-Hadamard transform, one block per row.
// 128 threads x 64 floats (16 x f32x4) per thread -> only 2 LDS round trips.
// Stage split: ph1 elem bits {0,1} (in-quad) + {9,10,11,12} (across k, load-contiguous),
//              ph2 bits {2,3,4,5}, ph3 bits {6,7,8} (m3 = spare owned bit).
// lds[2048] quads; quad q stored at swz(q)=q^((q>>4)&7) -- verified
// conflict-free for all 4 sweeps (each aligned 8-lane group permutes the 8
// bank-quad-groups).

typedef float f32x4 __attribute__((ext_vector_type(4)));

static __device__ __forceinline__ void bfly(f32x4& a, f32x4& b) {
    f32x4 t = a;
    a = t + b;
    b = t - b;
}

static __device__ __forceinline__ int swz(int q) { return q ^ ((q >> 4) & 7); }

__global__ __launch_bounds__(128) void wht8192_kernel(const float* __restrict__ in,
                                                      float* __restrict__ out) {
    __shared__ f32x4 lds[2048];  // 32 KB = one row
    const int t = threadIdx.x;   // 0..127
    const size_t row = blockIdx.x;
    const float* __restrict__ rin  = in  + row * 8192;
    float* __restrict__       rout = out + row * 8192;

    f32x4 v[16];

    // ---- phase 1: quads q = (k<<7)|t  (elements (k<<9)|(t<<2)) ----
    #pragma unroll
    for (int k = 0; k < 16; ++k)
        v[k] = __builtin_nontemporal_load(
            reinterpret_cast<const f32x4*>(rin + ((k << 9) | (t << 2))));

    // elem bits 0,1 (inside each quad)
    #pragma unroll
    for (int k = 0; k < 16; ++k) {
        f32x4 a = v[k];
        float s0 = a.x + a.y, d0 = a.x - a.y;
        float s1 = a.z + a.w, d1 = a.z - a.w;
        v[k].x = s0 + s1; v[k].z = s0 - s1;
        v[k].y = d0 + d1; v[k].w = d0 - d1;
    }
    // elem bits 9,10,11,12 (across k)
    #pragma unroll
    for (int s = 1; s < 16; s <<= 1) {
        #pragma unroll
        for (int m = 0; m < 16; ++m)
            if (!(m & s)) bfly(v[m], v[m | s]);
    }

    #pragma unroll
    for (int k = 0; k < 16; ++k)
        lds[swz((k << 7) | t)] = v[k];
    __syncthreads();

    // ---- phase 2: quads q = (t<<4)|j ; elem bits 2,3,4,5 ----
    #pragma unroll
    for (int j = 0; j < 16; ++j)
        v[j] = lds[swz((t << 4) | j)];

    #pragma unroll
    for (int s = 1; s < 16; s <<= 1) {
        #pragma unroll
        for (int m = 0; m < 16; ++m)
            if (!(m & s)) bfly(v[m], v[m | s]);
    }

    #pragma unroll
    for (int j = 0; j < 16; ++j)
        lds[swz((t << 4) | j)] = v[j];
    __syncthreads();

    // ---- phase 3: q = (m3<<10)|((t>>4)<<7)|(mL<<4)|(t&15); butterfly q bits
    //      {4,5,6} = elem bits {6,7,8}; m bit 3 (q bit 10) is a spare owned bit ----
    const int base3 = ((t >> 4) << 7) | (t & 15);
    #pragma unroll
    for (int m = 0; m < 16; ++m)
        v[m] = lds[swz(base3 | ((m >> 3) << 10) | ((m & 7) << 4))];

    // 3 stages across mL (pairs stay within the same m3 half: s = 1,2,4)
    #pragma unroll
    for (int s = 1; s < 8; s <<= 1) {
        #pragma unroll
        for (int m = 0; m < 16; ++m)
            if (!(m & s)) bfly(v[m], v[m | s]);
    }

    const float sc = 0.011048543456039806f;  // 1/sqrt(8192)
    #pragma unroll
    for (int m = 0; m < 16; ++m) {
        f32x4 a = v[m] * sc;
        const int q = base3 | ((m >> 3) << 10) | ((m & 7) << 4);
        __builtin_nontemporal_store(a, reinterpret_cast<f32x4*>(rout + (q << 2)));
    }
}

extern "C" void kernel_launch(void* const* d_in, const int* in_sizes, int n_in,
                              void* d_out, int out_size, void* d_ws, size_t ws_size,
                              hipStream_t stream) {
    const float* x = (const float*)d_in[0];
    float* out = (float*)d_out;
    const int rows = out_size / 8192;  // 8192
    hipLaunchKernelGGL(wht8192_kernel, dim3(rows), dim3(128), 0, stream, x, out);
}

// Round 4
// 93.946 us; speedup vs baseline: 1.1015x; 1.0031x over previous
//
#include <hip/hip_runtime.h>

// Batched 8192-point WHT, one block per row. 128 threads x 16 f32x4.
// Phases: ph1 = elem bits {0,1} (in-quad) + {9..12} (k = q bits 7..10, load-contig)
//         ph2 = elem bits {2..5}  (j = q bits 0..3)
//         ph3 = elem bits {6,7,8} (mL = q bits 4..6; m3 = q bit 10 spare)
// RT1 (ph1->ph2) is INTRA-WAVE: ph2 ownership q=(tL<<7)|(g<<4)|j keeps the
// exchange inside 16-thread groups sharing g = t>>4 (q bits 4..6 fixed),
// so a lgkmcnt(0) replaces the first __syncthreads. RT2 (ph2->ph3) is
// cross-wave and keeps the single block barrier.
// Swizzle swz(q) = q ^ (((q>>4)^(q>>7))&7): verified conflict-free for all
// sweeps (each aligned 8-lane run permutes the 8 bank-quad-groups).

typedef float f32x4 __attribute__((ext_vector_type(4)));

static __device__ __forceinline__ void bfly(f32x4& a, f32x4& b) {
    f32x4 t = a;
    a = t + b;
    b = t - b;
}

static __device__ __forceinline__ int swz(int q) {
    return q ^ (((q >> 4) ^ (q >> 7)) & 7);
}

__global__ __launch_bounds__(128) void wht8192_kernel(const float* __restrict__ in,
                                                      float* __restrict__ out) {
    __shared__ f32x4 lds[2048];  // 32 KB = one row
    const int t  = threadIdx.x;  // 0..127
    const int tL = t & 15;
    const int g  = t >> 4;       // 3 bits
    const size_t row = blockIdx.x;
    const float* __restrict__ rin  = in  + row * 8192;
    float* __restrict__       rout = out + row * 8192;

    f32x4 v[16];

    // ---- phase 1: quads q = (k<<7)|t  (elements (k<<9)|(t<<2)) ----
    #pragma unroll
    for (int k = 0; k < 16; ++k)
        v[k] = __builtin_nontemporal_load(
            reinterpret_cast<const f32x4*>(rin + ((k << 9) | (t << 2))));

    // elem bits 0,1 (inside each quad)
    #pragma unroll
    for (int k = 0; k < 16; ++k) {
        f32x4 a = v[k];
        float s0 = a.x + a.y, d0 = a.x - a.y;
        float s1 = a.z + a.w, d1 = a.z - a.w;
        v[k].x = s0 + s1; v[k].z = s0 - s1;
        v[k].y = d0 + d1; v[k].w = d0 - d1;
    }
    // elem bits 9,10,11,12 (across k)
    #pragma unroll
    for (int s = 1; s < 16; s <<= 1) {
        #pragma unroll
        for (int m = 0; m < 16; ++m)
            if (!(m & s)) bfly(v[m], v[m | s]);
    }

    #pragma unroll
    for (int k = 0; k < 16; ++k)
        lds[swz((k << 7) | t)] = v[k];

    // RT1 is intra-wave (16-thread groups sharing g): no block barrier needed.
    asm volatile("s_waitcnt lgkmcnt(0)" ::: "memory");

    // ---- phase 2: quads q = (tL<<7)|(g<<4)|j ; elem bits 2,3,4,5 ----
    const int base2 = (tL << 7) | (g << 4);
    #pragma unroll
    for (int j = 0; j < 16; ++j)
        v[j] = lds[swz(base2 | j)];

    #pragma unroll
    for (int s = 1; s < 16; s <<= 1) {
        #pragma unroll
        for (int m = 0; m < 16; ++m)
            if (!(m & s)) bfly(v[m], v[m | s]);
    }

    #pragma unroll
    for (int j = 0; j < 16; ++j)
        lds[swz(base2 | j)] = v[j];
    __syncthreads();

    // ---- phase 3: q = (m3<<10)|(g<<7)|(mL<<4)|tL ; butterfly q bits {4,5,6}
    //      = elem bits {6,7,8}; m bit 3 (q bit 10) is a spare owned bit ----
    const int base3 = (g << 7) | tL;
    #pragma unroll
    for (int m = 0; m < 16; ++m)
        v[m] = lds[swz(base3 | ((m >> 3) << 10) | ((m & 7) << 4))];

    // 3 stages across mL (s = 1,2,4; pairs stay within the same m3 half)
    #pragma unroll
    for (int s = 1; s < 8; s <<= 1) {
        #pragma unroll
        for (int m = 0; m < 16; ++m)
            if (!(m & s)) bfly(v[m], v[m | s]);
    }

    const float sc = 0.011048543456039806f;  // 1/sqrt(8192)
    #pragma unroll
    for (int m = 0; m < 16; ++m) {
        f32x4 a = v[m] * sc;
        const int q = base3 | ((m >> 3) << 10) | ((m & 7) << 4);
        __builtin_nontemporal_store(a, reinterpret_cast<f32x4*>(rout + (q << 2)));
    }
}

extern "C" void kernel_launch(void* const* d_in, const int* in_sizes, int n_in,
                              void* d_out, int out_size, void* d_ws, size_t ws_size,
                              hipStream_t stream) {
    const float* x = (const float*)d_in[0];
    float* out = (float*)d_out;
    const int rows = out_size / 8192;  // 8192
    hipLaunchKernelGGL(wht8192_kernel, dim3(rows), dim3(128), 0, stream, x, out);
}

// Round 5
// 88.107 us; speedup vs baseline: 1.1745x; 1.0663x over previous
//
#include <hip/hip_runtime.h>

// Batched 8192-point WHT, one block per row. 128 threads x 16 f32x4.
// Phases: ph1 = elem bits {0,1} (in-quad) + {9..12} (k = q bits 7..10, load-contig)
//         ph2 = elem bits {2..5}  (j = q bits 0..3)
//         ph3 = elem bits {6,7,8} (mL = q bits 4..6; m3 = q bit 10 spare)
// RT1 (ph1->ph2) is intra-wave (16-thread groups sharing g=t>>4) -> lgkmcnt(0)
// instead of a barrier. RT2 keeps the single block barrier.
// Swizzle swz(q) = q ^ (((q>>4)^(q>>7))&7): conflict-free for all sweeps.
// R4 change: loads are CACHED (input is re-read every graph replay; 256 MiB
// input == LLC size), stores stay nontemporal (write-once, don't allocate).

typedef float f32x4 __attribute__((ext_vector_type(4)));

static __device__ __forceinline__ void bfly(f32x4& a, f32x4& b) {
    f32x4 t = a;
    a = t + b;
    b = t - b;
}

static __device__ __forceinline__ int swz(int q) {
    return q ^ (((q >> 4) ^ (q >> 7)) & 7);
}

__global__ __launch_bounds__(128) void wht8192_kernel(const float* __restrict__ in,
                                                      float* __restrict__ out) {
    __shared__ f32x4 lds[2048];  // 32 KB = one row
    const int t  = threadIdx.x;  // 0..127
    const int tL = t & 15;
    const int g  = t >> 4;       // 3 bits
    const size_t row = blockIdx.x;
    const float* __restrict__ rin  = in  + row * 8192;
    float* __restrict__       rout = out + row * 8192;

    f32x4 v[16];

    // ---- phase 1: quads q = (k<<7)|t  (elements (k<<9)|(t<<2)) ----
    #pragma unroll
    for (int k = 0; k < 16; ++k)
        v[k] = *reinterpret_cast<const f32x4*>(rin + ((k << 9) | (t << 2)));

    // elem bits 0,1 (inside each quad)
    #pragma unroll
    for (int k = 0; k < 16; ++k) {
        f32x4 a = v[k];
        float s0 = a.x + a.y, d0 = a.x - a.y;
        float s1 = a.z + a.w, d1 = a.z - a.w;
        v[k].x = s0 + s1; v[k].z = s0 - s1;
        v[k].y = d0 + d1; v[k].w = d0 - d1;
    }
    // elem bits 9,10,11,12 (across k)
    #pragma unroll
    for (int s = 1; s < 16; s <<= 1) {
        #pragma unroll
        for (int m = 0; m < 16; ++m)
            if (!(m & s)) bfly(v[m], v[m | s]);
    }

    #pragma unroll
    for (int k = 0; k < 16; ++k)
        lds[swz((k << 7) | t)] = v[k];

    // RT1 is intra-wave (16-thread groups sharing g): no block barrier needed.
    asm volatile("s_waitcnt lgkmcnt(0)" ::: "memory");

    // ---- phase 2: quads q = (tL<<7)|(g<<4)|j ; elem bits 2,3,4,5 ----
    const int base2 = (tL << 7) | (g << 4);
    #pragma unroll
    for (int j = 0; j < 16; ++j)
        v[j] = lds[swz(base2 | j)];

    #pragma unroll
    for (int s = 1; s < 16; s <<= 1) {
        #pragma unroll
        for (int m = 0; m < 16; ++m)
            if (!(m & s)) bfly(v[m], v[m | s]);
    }

    #pragma unroll
    for (int j = 0; j < 16; ++j)
        lds[swz(base2 | j)] = v[j];
    __syncthreads();

    // ---- phase 3: q = (m3<<10)|(g<<7)|(mL<<4)|tL ; butterfly q bits {4,5,6}
    //      = elem bits {6,7,8}; m bit 3 (q bit 10) is a spare owned bit ----
    const int base3 = (g << 7) | tL;
    #pragma unroll
    for (int m = 0; m < 16; ++m)
        v[m] = lds[swz(base3 | ((m >> 3) << 10) | ((m & 7) << 4))];

    // 3 stages across mL (s = 1,2,4; pairs stay within the same m3 half)
    #pragma unroll
    for (int s = 1; s < 8; s <<= 1) {
        #pragma unroll
        for (int m = 0; m < 16; ++m)
            if (!(m & s)) bfly(v[m], v[m | s]);
    }

    const float sc = 0.011048543456039806f;  // 1/sqrt(8192)
    #pragma unroll
    for (int m = 0; m < 16; ++m) {
        f32x4 a = v[m] * sc;
        const int q = base3 | ((m >> 3) << 10) | ((m & 7) << 4);
        __builtin_nontemporal_store(a, reinterpret_cast<f32x4*>(rout + (q << 2)));
    }
}

extern "C" void kernel_launch(void* const* d_in, const int* in_sizes, int n_in,
                              void* d_out, int out_size, void* d_ws, size_t ws_size,
                              hipStream_t stream) {
    const float* x = (const float*)d_in[0];
    float* out = (float*)d_out;
    const int rows = out_size / 8192;  // 8192
    hipLaunchKernelGGL(wht8192_kernel, dim3(rows), dim3(128), 0, stream, x, out);
}

// Round 7
// 87.654 us; speedup vs baseline: 1.1806x; 1.0052x over previous
//
#include <hip/hip_runtime.h>

// Batched 8192-point WHT, one block per row. 128 threads x 16 f32x4.
// Phases: ph1 = elem bits {0,1} (in-quad) + {9..12} (k = q bits 7..10, load-contig)
//         ph2 = elem bits {2..5}  (j = q bits 0..3)
//         ph3 = elem bits {6,7,8} (mL = q bits 4..6; m3 = q bit 10 spare)
// RT1 (ph1->ph2) is intra-wave (16-thread groups sharing g=t>>4) -> lgkmcnt(0)
// instead of a barrier. RT2 keeps the single block barrier.
// Swizzle swz(q) = q ^ (((q>>4)^(q>>7))&7): conflict-free for all sweeps.
// Loads CACHED (input re-read every replay; 256 MiB == LLC -> ~50% LLC hits,
// FETCH_SIZE ~128 MiB). Stores nontemporal via builtin (coherent, unlike the
// R5 sc1 experiment which raced the harness's L2-dirty memset lines).

typedef float f32x4 __attribute__((ext_vector_type(4)));

static __device__ __forceinline__ void bfly(f32x4& a, f32x4& b) {
    f32x4 t = a;
    a = t + b;
    b = t - b;
}

static __device__ __forceinline__ int swz(int q) {
    return q ^ (((q >> 4) ^ (q >> 7)) & 7);
}

__global__ __launch_bounds__(128) void wht8192_kernel(const float* __restrict__ in,
                                                      float* __restrict__ out) {
    __shared__ f32x4 lds[2048];  // 32 KB = one row
    const int t  = threadIdx.x;  // 0..127
    const int tL = t & 15;
    const int g  = t >> 4;       // 3 bits
    const size_t row = blockIdx.x;
    const float* __restrict__ rin  = in  + row * 8192;
    float* __restrict__       rout = out + row * 8192;

    f32x4 v[16];

    // ---- phase 1: quads q = (k<<7)|t  (elements (k<<9)|(t<<2)) ----
    #pragma unroll
    for (int k = 0; k < 16; ++k)
        v[k] = *reinterpret_cast<const f32x4*>(rin + ((k << 9) | (t << 2)));

    // elem bits 0,1 (inside each quad)
    #pragma unroll
    for (int k = 0; k < 16; ++k) {
        f32x4 a = v[k];
        float s0 = a.x + a.y, d0 = a.x - a.y;
        float s1 = a.z + a.w, d1 = a.z - a.w;
        v[k].x = s0 + s1; v[k].z = s0 - s1;
        v[k].y = d0 + d1; v[k].w = d0 - d1;
    }
    // elem bits 9,10,11,12 (across k)
    #pragma unroll
    for (int s = 1; s < 16; s <<= 1) {
        #pragma unroll
        for (int m = 0; m < 16; ++m)
            if (!(m & s)) bfly(v[m], v[m | s]);
    }

    #pragma unroll
    for (int k = 0; k < 16; ++k)
        lds[swz((k << 7) | t)] = v[k];

    // RT1 is intra-wave (16-thread groups sharing g): no block barrier needed.
    asm volatile("s_waitcnt lgkmcnt(0)" ::: "memory");

    // ---- phase 2: quads q = (tL<<7)|(g<<4)|j ; elem bits 2,3,4,5 ----
    const int base2 = (tL << 7) | (g << 4);
    #pragma unroll
    for (int j = 0; j < 16; ++j)
        v[j] = lds[swz(base2 | j)];

    #pragma unroll
    for (int s = 1; s < 16; s <<= 1) {
        #pragma unroll
        for (int m = 0; m < 16; ++m)
            if (!(m & s)) bfly(v[m], v[m | s]);
    }

    #pragma unroll
    for (int j = 0; j < 16; ++j)
        lds[swz(base2 | j)] = v[j];
    __syncthreads();

    // ---- phase 3: q = (m3<<10)|(g<<7)|(mL<<4)|tL ; butterfly q bits {4,5,6}
    //      = elem bits {6,7,8}; m bit 3 (q bit 10) is a spare owned bit ----
    const int base3 = (g << 7) | tL;
    #pragma unroll
    for (int m = 0; m < 16; ++m)
        v[m] = lds[swz(base3 | ((m >> 3) << 10) | ((m & 7) << 4))];

    // 3 stages across mL (s = 1,2,4; pairs stay within the same m3 half)
    #pragma unroll
    for (int s = 1; s < 8; s <<= 1) {
        #pragma unroll
        for (int m = 0; m < 16; ++m)
            if (!(m & s)) bfly(v[m], v[m | s]);
    }

    const float sc = 0.011048543456039806f;  // 1/sqrt(8192)
    #pragma unroll
    for (int m = 0; m < 16; ++m) {
        f32x4 a = v[m] * sc;
        const int q = base3 | ((m >> 3) << 10) | ((m & 7) << 4);
        __builtin_nontemporal_store(a, reinterpret_cast<f32x4*>(rout + (q << 2)));
    }
}

extern "C" void kernel_launch(void* const* d_in, const int* in_sizes, int n_in,
                              void* d_out, int out_size, void* d_ws, size_t ws_size,
                              hipStream_t stream) {
    const float* x = (const float*)d_in[0];
    float* out = (float*)d_out;
    const int rows = out_size / 8192;  // 8192
    hipLaunchKernelGGL(wht8192_kernel, dim3(rows), dim3(128), 0, stream, x, out);
}